// Round 10
// baseline (332.111 us; speedup 1.0000x reference)
//
#include <hip/hip_runtime.h>

#define NN 50000
#define NE 800000
#define HD 128
#define NBK 98     // ceil(NN/512) dst-buckets
#define BCAP 16384 // fixed pairs capacity per bucket (mean 8163, +91 sigma)
#define FB 196     // fill1 edge blocks (196*4096 >= NE)

using short8 = __attribute__((ext_vector_type(8))) short;
using f32x4  = __attribute__((ext_vector_type(4))) float;

__device__ inline unsigned short rne_bf16(float v) {
    union { float f; unsigned u; } c; c.f = v;
    return (unsigned short)((c.u + 0x7fff + ((c.u >> 16) & 1)) >> 16);
}
__device__ inline float bf16_to_f32(unsigned short h) {
    union { unsigned u; float f; } c; c.u = ((unsigned)h) << 16;
    return c.f;
}

// ---------------- 1: degree count ----------------

__global__ void k_deg_count(const int* __restrict__ row, int* __restrict__ deg) {
    int e = blockIdx.x * 256 + threadIdx.x;
    if (e < NE) atomicAdd(&deg[row[e]], 1);
}

// ---------------- 2: bin edges into fixed-capacity buckets (+ folded prepw) --------
// blocks [0,FB): binning. blocks [FB,FB+16): weight-fragment prep.

__global__ __launch_bounds__(256) void k_fill1(const int* __restrict__ ei,
                                               int* __restrict__ bcur,
                                               int2* __restrict__ pairs,
                                               const float* __restrict__ W1,
                                               const float* __restrict__ W2,
                                               unsigned short* __restrict__ hi1,
                                               unsigned short* __restrict__ lo1,
                                               unsigned short* __restrict__ hi2,
                                               unsigned short* __restrict__ lo2) {
    int t = threadIdx.x, b = blockIdx.x;
    if (b >= FB) {  // ---- prepw path ----
        int bb = b - FB;
        const float* W = (bb < 8) ? W1 : W2;
        unsigned short* hi = (bb < 8) ? hi1 : hi2;
        unsigned short* lo = (bb < 8) ? lo1 : lo2;
        int tid = (bb & 7) * 256 + t;  // 0..2047
        int lane = tid & 63;
        int ks = (tid >> 6) & 3;
        int nt = tid >> 8;
        int n = nt * 16 + (lane & 15);
        int k0 = ks * 32 + (lane >> 4) * 8;
#pragma unroll
        for (int j = 0; j < 8; ++j) {
            float v = W[(k0 + j) * HD + n];
            unsigned short h = rne_bf16(v);
            float rem = v - bf16_to_f32(h);
            hi[(size_t)tid * 8 + j] = h;
            lo[(size_t)tid * 8 + j] = rne_bf16(rem);
        }
        return;
    }
    // ---- binning path ----
    __shared__ int dr[4096], sc[4096];
    __shared__ int hist[NBK], base[NBK];
    for (int i = t; i < NBK; i += 256) hist[i] = 0;
    __syncthreads();
    int e0 = b * 4096;
#pragma unroll
    for (int u = 0; u < 16; ++u) {
        int idx = u * 256 + t, e = e0 + idx;
        int r = -1, c = 0;
        if (e < NE) {
            r = ei[e];
            c = ei[NE + e];
            atomicAdd(&hist[r >> 9], 1);
        }
        dr[idx] = r;
        sc[idx] = c;
    }
    __syncthreads();
    for (int i = t; i < NBK; i += 256) {
        base[i] = atomicAdd(&bcur[i], hist[i]);  // bcur zero-init; relative base
        hist[i] = 0;
    }
    __syncthreads();
#pragma unroll
    for (int u = 0; u < 16; ++u) {
        int idx = u * 256 + t;
        int r = dr[idx];
        if (r >= 0) {
            int bk = r >> 9;
            int pos = atomicAdd(&hist[bk], 1);
            pairs[(size_t)bk * BCAP + base[bk] + pos] = make_int2(r, sc[idx]);
        }
    }
}

// ---------------- 3: per-bucket finalize — offs + dinv + csr scatter ----------------
// block b owns nodes [b*512, b*512+512): computes base = sum(deg[0..n0)) directly,
// in-LDS scan of its 512 degs, writes offs/dinv, scatters its pairs into csr.

__global__ __launch_bounds__(256) void k_fill2(const int2* __restrict__ pairs,
                                               const int* __restrict__ deg,
                                               int* __restrict__ offs,
                                               float* __restrict__ dinv,
                                               int* __restrict__ csr) {
    __shared__ int spart[256];
    __shared__ int lcur[512];
    int b = blockIdx.x, t = threadIdx.x;
    int n0 = b * 512;
    int nodes = min(512, NN - n0);

    // base = sum of deg[0..n0)
    int accb = 0;
    for (int i = t; i < n0; i += 256) accb += deg[i];
    spart[t] = accb;
    __syncthreads();
#pragma unroll
    for (int o = 128; o > 0; o >>= 1) {
        if (t < o) spart[t] += spart[t + o];
        __syncthreads();
    }
    int base = spart[0];
    __syncthreads();

    // scan own 512 degs (2 per thread)
    int d0 = (2 * t < nodes) ? deg[n0 + 2 * t] : 0;
    int d1 = (2 * t + 1 < nodes) ? deg[n0 + 2 * t + 1] : 0;
    spart[t] = d0 + d1;
    __syncthreads();
#pragma unroll
    for (int o = 1; o < 256; o <<= 1) {
        int x = (t >= o) ? spart[t - o] : 0;
        __syncthreads();
        spart[t] += x;
        __syncthreads();
    }
    int excl = spart[t] - (d0 + d1);
    int tot = spart[255];
    int o0 = base + excl, o1 = o0 + d0;
    if (2 * t < nodes) {
        offs[n0 + 2 * t] = o0;
        lcur[2 * t] = o0;
        dinv[n0 + 2 * t] = rsqrtf((float)(d0 + 1));
    }
    if (2 * t + 1 < nodes) {
        offs[n0 + 2 * t + 1] = o1;
        lcur[2 * t + 1] = o1;
        dinv[n0 + 2 * t + 1] = rsqrtf((float)(d1 + 1));
    }
    __syncthreads();

    // scatter this bucket's pairs into csr via LDS cursors
    const int2* pp = pairs + (size_t)b * BCAP;
    for (int p = t; p < tot; p += 256) {
        int2 pr = pp[p];
        int slot = atomicAdd(&lcur[pr.x - n0], 1);
        csr[slot] = pr.y;
    }
}

// ---------------- aggregation: one wave/node, float4 gathers (R7-proven) ----------

__global__ __launch_bounds__(256) void k_agg_csr(const float* __restrict__ src,
                                                 const int* __restrict__ csr,
                                                 const int* __restrict__ offs,
                                                 const int* __restrict__ deg,
                                                 const float* __restrict__ dinv,
                                                 float* __restrict__ dst) {
    int node = blockIdx.x * 4 + (threadIdx.x >> 6);
    int lane = threadIdx.x & 63;
    int half = lane >> 5;
    int q = lane & 31;  // float4 column index
    int o = offs[node];
    int dg = deg[node];
    float d = dinv[node];

    float4 acc = make_float4(0.f, 0.f, 0.f, 0.f);
    if (half == 0) {
        float s = d * d;
        float4 v = ((const float4*)(src + (size_t)node * HD))[q];
        acc = make_float4(s * v.x, s * v.y, s * v.z, s * v.w);
    }

    for (int base = 0; base < dg; base += 64) {
        int n = min(64, dg - base);
        int myc = (lane < n) ? csr[o + base + lane] : node;
        float myw = (lane < n) ? d * dinv[myc] : 0.0f;
        for (int j = 0; j < n; j += 16) {
            int c[8];
            float w[8];
#pragma unroll
            for (int p = 0; p < 8; ++p) {
                c[p] = __shfl(myc, j + 2 * p + half);
                w[p] = __shfl(myw, j + 2 * p + half);
            }
            float4 v[8];
#pragma unroll
            for (int p = 0; p < 8; ++p)
                v[p] = *(const float4*)(src + (size_t)c[p] * HD + q * 4);
#pragma unroll
            for (int p = 0; p < 8; ++p) {
                acc.x = fmaf(w[p], v[p].x, acc.x);
                acc.y = fmaf(w[p], v[p].y, acc.y);
                acc.z = fmaf(w[p], v[p].z, acc.z);
                acc.w = fmaf(w[p], v[p].w, acc.w);
            }
        }
    }

    float ox = acc.x + __shfl(acc.x, q + 32);
    float oy = acc.y + __shfl(acc.y, q + 32);
    float oz = acc.z + __shfl(acc.z, q + 32);
    float ow = acc.w + __shfl(acc.w, q + 32);
    if (half == 0)
        ((float4*)(dst + (size_t)node * HD))[q] = make_float4(ox, oy, oz, ow);
}

// ---------------- MFMA GEMM (split-bf16, fp32-accurate) ----------------

template <bool RELU>
__global__ __launch_bounds__(256) void k_gemm_mfma(const float* __restrict__ A,
                                                   const unsigned short* __restrict__ Whi,
                                                   const unsigned short* __restrict__ Wlo,
                                                   const float* __restrict__ bias,
                                                   float* __restrict__ C, int nrows) {
    int l = threadIdx.x & 63;
    int w = threadIdx.x >> 6;
    int row0 = blockIdx.x * 64 + w * 16;
    int arow = row0 + (l & 15);
    int kj = (l >> 4) * 8;
    bool avalid = (arow < nrows);
    const float* ap = A + (size_t)(avalid ? arow : 0) * HD + kj;

    f32x4 acc[8];
#pragma unroll
    for (int nt = 0; nt < 8; ++nt) acc[nt] = (f32x4){0.f, 0.f, 0.f, 0.f};

#pragma unroll
    for (int ks = 0; ks < 4; ++ks) {
        float4 a0 = make_float4(0.f, 0.f, 0.f, 0.f), a1 = a0;
        if (avalid) {
            a0 = *(const float4*)(ap + ks * 32);
            a1 = *(const float4*)(ap + ks * 32 + 4);
        }
        float av[8] = {a0.x, a0.y, a0.z, a0.w, a1.x, a1.y, a1.z, a1.w};
        short8 ahi, alo;
#pragma unroll
        for (int j = 0; j < 8; ++j) {
            unsigned short h = rne_bf16(av[j]);
            ahi[j] = (short)h;
            alo[j] = (short)rne_bf16(av[j] - bf16_to_f32(h));
        }
#pragma unroll
        for (int nt = 0; nt < 8; ++nt) {
            size_t fo = ((size_t)(nt * 4 + ks) * 64 + l) * 8;
            short8 bhi = *(const short8*)(Whi + fo);
            short8 blo = *(const short8*)(Wlo + fo);
            acc[nt] = __builtin_amdgcn_mfma_f32_16x16x32_bf16(ahi, bhi, acc[nt], 0, 0, 0);
            acc[nt] = __builtin_amdgcn_mfma_f32_16x16x32_bf16(alo, bhi, acc[nt], 0, 0, 0);
            acc[nt] = __builtin_amdgcn_mfma_f32_16x16x32_bf16(ahi, blo, acc[nt], 0, 0, 0);
        }
    }

#pragma unroll
    for (int nt = 0; nt < 8; ++nt) {
        int col = nt * 16 + (l & 15);
        float bv = bias[col];
#pragma unroll
        for (int r = 0; r < 4; ++r) {
            int gr = row0 + (l >> 4) * 4 + r;
            if (gr >= nrows) continue;
            float v = acc[nt][r] + bv;
            if (RELU) v = fmaxf(v, 0.f);
            C[(size_t)gr * HD + col] = v;
        }
    }
}

// ---------------- launch ----------------

extern "C" void kernel_launch(void* const* d_in, const int* in_sizes, int n_in,
                              void* d_out, int out_size, void* d_ws, size_t ws_size,
                              hipStream_t stream) {
    const float* x  = (const float*)d_in[0];
    const int*   ei = (const int*)d_in[1];
    const float* W1 = (const float*)d_in[2];
    const float* b1 = (const float*)d_in[3];
    const float* W2 = (const float*)d_in[4];
    const float* b2 = (const float*)d_in[5];
    float* out = (float*)d_out;

    char* ws = (char*)d_ws;
    size_t off = 0;
    auto alloc = [&](size_t bytes) {
        void* p = ws + off;
        off = (off + bytes + 255) & ~(size_t)255;
        return p;
    };
    int*   deg  = (int*)alloc(NN * 4);             // zeroed by memset (with bcur)
    int*   bcur = (int*)alloc(NBK * 4);
    size_t zspan = off;                            // deg..bcur span to zero
    int*   offs = (int*)alloc(NN * 4);
    float* dinv = (float*)alloc(NN * 4);
    int*   csr  = (int*)alloc((size_t)NE * 4);
    // pairs and h overlap: pairs (12.85MB) dead before gemm1 writes h (25.6MB)
    char*  region = (char*)alloc((size_t)NN * HD * 4);
    int2*  pairs = (int2*)region;
    float* h     = (float*)region;
    float* t1   = (float*)alloc((size_t)NN * HD * 4);
    unsigned short* Whi1 = (unsigned short*)alloc(16384 * 2);
    unsigned short* Wlo1 = (unsigned short*)alloc(16384 * 2);
    unsigned short* Whi2 = (unsigned short*)alloc(16384 * 2);
    unsigned short* Wlo2 = (unsigned short*)alloc(16384 * 2);

    // CSR build: 3 dispatches + 1 memset
    hipMemsetAsync(deg, 0, zspan, stream);
    k_deg_count<<<(NE + 255) / 256, 256, 0, stream>>>(ei, deg);
    k_fill1<<<FB + 16, 256, 0, stream>>>(ei, bcur, pairs, W1, W2, Whi1, Wlo1, Whi2, Wlo2);
    k_fill2<<<NBK, 256, 0, stream>>>(pairs, deg, offs, dinv, csr);

    // conv1: t1 = agg(x); h = relu(t1@W1 + b1)
    k_agg_csr<<<NN / 4, 256, 0, stream>>>(x, csr, offs, deg, dinv, t1);
    k_gemm_mfma<true><<<(NN + 63) / 64, 256, 0, stream>>>(t1, Whi1, Wlo1, b1, h, NN);

    // conv2: t1 = agg(h); out = t1@W2 + b2
    k_agg_csr<<<NN / 4, 256, 0, stream>>>(h, csr, offs, deg, dinv, t1);
    k_gemm_mfma<false><<<(NN + 63) / 64, 256, 0, stream>>>(t1, Whi2, Wlo2, b2, out, NN);
}

// Round 11
// 279.398 us; speedup vs baseline: 1.1887x; 1.1887x over previous
//
#include <hip/hip_runtime.h>

#define NN 50000
#define NE 800000
#define HD 128
#define NBK 98     // ceil(NN/512) dst-buckets
#define BCAP 16384 // fixed pairs capacity per bucket (mean 8163, +91 sigma)
#define FB 196     // fill1 edge blocks (196*4096 >= NE)

using short8 = __attribute__((ext_vector_type(8))) short;
using f32x4  = __attribute__((ext_vector_type(4))) float;

__device__ inline unsigned short rne_bf16(float v) {
    union { float f; unsigned u; } c; c.f = v;
    return (unsigned short)((c.u + 0x7fff + ((c.u >> 16) & 1)) >> 16);
}
__device__ inline float bf16_to_f32(unsigned short h) {
    union { unsigned u; float f; } c; c.u = ((unsigned)h) << 16;
    return c.f;
}

// ---------------- 1: bin edges into fixed-capacity buckets (+ folded prepw) --------
// blocks [0,FB): binning. blocks [FB,FB+16): weight-fragment prep.

__global__ __launch_bounds__(256) void k_fill1(const int* __restrict__ ei,
                                               int* __restrict__ bcur,
                                               int2* __restrict__ pairs,
                                               const float* __restrict__ W1,
                                               const float* __restrict__ W2,
                                               unsigned short* __restrict__ hi1,
                                               unsigned short* __restrict__ lo1,
                                               unsigned short* __restrict__ hi2,
                                               unsigned short* __restrict__ lo2) {
    int t = threadIdx.x, b = blockIdx.x;
    if (b >= FB) {  // ---- prepw path ----
        int bb = b - FB;
        const float* W = (bb < 8) ? W1 : W2;
        unsigned short* hi = (bb < 8) ? hi1 : hi2;
        unsigned short* lo = (bb < 8) ? lo1 : lo2;
        int tid = (bb & 7) * 256 + t;  // 0..2047
        int lane = tid & 63;
        int ks = (tid >> 6) & 3;
        int nt = tid >> 8;
        int n = nt * 16 + (lane & 15);
        int k0 = ks * 32 + (lane >> 4) * 8;
#pragma unroll
        for (int j = 0; j < 8; ++j) {
            float v = W[(k0 + j) * HD + n];
            unsigned short h = rne_bf16(v);
            float rem = v - bf16_to_f32(h);
            hi[(size_t)tid * 8 + j] = h;
            lo[(size_t)tid * 8 + j] = rne_bf16(rem);
        }
        return;
    }
    // ---- binning path ----
    __shared__ int dr[4096], sc[4096];
    __shared__ int hist[NBK], base[NBK];
    for (int i = t; i < NBK; i += 256) hist[i] = 0;
    __syncthreads();
    int e0 = b * 4096;
#pragma unroll
    for (int u = 0; u < 16; ++u) {
        int idx = u * 256 + t, e = e0 + idx;
        int r = -1, c = 0;
        if (e < NE) {
            r = ei[e];
            c = ei[NE + e];
            atomicAdd(&hist[r >> 9], 1);
        }
        dr[idx] = r;
        sc[idx] = c;
    }
    __syncthreads();
    for (int i = t; i < NBK; i += 256) {
        base[i] = atomicAdd(&bcur[i], hist[i]);  // bcur zero-init; relative base
        hist[i] = 0;
    }
    __syncthreads();
#pragma unroll
    for (int u = 0; u < 16; ++u) {
        int idx = u * 256 + t;
        int r = dr[idx];
        if (r >= 0) {
            int bk = r >> 9;
            int pos = atomicAdd(&hist[bk], 1);
            pairs[(size_t)bk * BCAP + base[bk] + pos] = make_int2(r, sc[idx]);
        }
    }
}

// ---------------- 2: per-bucket finalize — deg (from pairs) + offs + dinv + csr ------
// block b owns nodes [b*512, b*512+512). base = sum(bcur[0..b)); per-node deg via
// LDS atomics over this bucket's pairs; LDS scan; write deg/offs/dinv; scatter csr.

__global__ __launch_bounds__(256) void k_fill2(const int2* __restrict__ pairs,
                                               const int* __restrict__ bcur,
                                               int* __restrict__ deg,
                                               int* __restrict__ offs,
                                               float* __restrict__ dinv,
                                               int* __restrict__ csr) {
    __shared__ int spart[256];
    __shared__ int cnt[512];
    __shared__ int lcur[512];
    int b = blockIdx.x, t = threadIdx.x;
    int n0 = b * 512;
    int nodes = min(512, NN - n0);

    // base = sum of bucket totals before b
    int v = (t < NBK && t < b) ? bcur[t] : 0;
    spart[t] = v;
    __syncthreads();
#pragma unroll
    for (int o = 128; o > 0; o >>= 1) {
        if (t < o) spart[t] += spart[t + o];
        __syncthreads();
    }
    int base = spart[0];
    int tot = bcur[b];

    // per-node degree via LDS atomics over this bucket's pairs
    for (int i = t; i < 512; i += 256) cnt[i] = 0;
    __syncthreads();
    const int2* pp = pairs + (size_t)b * BCAP;
    for (int p = t; p < tot; p += 256) atomicAdd(&cnt[pp[p].x - n0], 1);
    __syncthreads();

    // scan own 512 degs (2 per thread)
    int d0 = (2 * t < nodes) ? cnt[2 * t] : 0;
    int d1 = (2 * t + 1 < nodes) ? cnt[2 * t + 1] : 0;
    spart[t] = d0 + d1;
    __syncthreads();
#pragma unroll
    for (int o = 1; o < 256; o <<= 1) {
        int x = (t >= o) ? spart[t - o] : 0;
        __syncthreads();
        spart[t] += x;
        __syncthreads();
    }
    int excl = spart[t] - (d0 + d1);
    int o0 = base + excl, o1 = o0 + d0;
    if (2 * t < nodes) {
        offs[n0 + 2 * t] = o0;
        lcur[2 * t] = o0;
        deg[n0 + 2 * t] = d0;
        dinv[n0 + 2 * t] = rsqrtf((float)(d0 + 1));
    }
    if (2 * t + 1 < nodes) {
        offs[n0 + 2 * t + 1] = o1;
        lcur[2 * t + 1] = o1;
        deg[n0 + 2 * t + 1] = d1;
        dinv[n0 + 2 * t + 1] = rsqrtf((float)(d1 + 1));
    }
    __syncthreads();

    // scatter this bucket's pairs into csr via LDS cursors
    for (int p = t; p < tot; p += 256) {
        int2 pr = pp[p];
        int slot = atomicAdd(&lcur[pr.x - n0], 1);
        csr[slot] = pr.y;
    }
}

// ---------------- aggregation: one wave/node, float4 gathers (R7-proven) ----------

__global__ __launch_bounds__(256) void k_agg_csr(const float* __restrict__ src,
                                                 const int* __restrict__ csr,
                                                 const int* __restrict__ offs,
                                                 const int* __restrict__ deg,
                                                 const float* __restrict__ dinv,
                                                 float* __restrict__ dst) {
    int node = blockIdx.x * 4 + (threadIdx.x >> 6);
    int lane = threadIdx.x & 63;
    int half = lane >> 5;
    int q = lane & 31;  // float4 column index
    int o = offs[node];
    int dg = deg[node];
    float d = dinv[node];

    float4 acc = make_float4(0.f, 0.f, 0.f, 0.f);
    if (half == 0) {
        float s = d * d;
        float4 v = ((const float4*)(src + (size_t)node * HD))[q];
        acc = make_float4(s * v.x, s * v.y, s * v.z, s * v.w);
    }

    for (int base = 0; base < dg; base += 64) {
        int n = min(64, dg - base);
        int myc = (lane < n) ? csr[o + base + lane] : node;
        float myw = (lane < n) ? d * dinv[myc] : 0.0f;
        for (int j = 0; j < n; j += 16) {
            int c[8];
            float w[8];
#pragma unroll
            for (int p = 0; p < 8; ++p) {
                c[p] = __shfl(myc, j + 2 * p + half);
                w[p] = __shfl(myw, j + 2 * p + half);
            }
            float4 v[8];
#pragma unroll
            for (int p = 0; p < 8; ++p)
                v[p] = *(const float4*)(src + (size_t)c[p] * HD + q * 4);
#pragma unroll
            for (int p = 0; p < 8; ++p) {
                acc.x = fmaf(w[p], v[p].x, acc.x);
                acc.y = fmaf(w[p], v[p].y, acc.y);
                acc.z = fmaf(w[p], v[p].z, acc.z);
                acc.w = fmaf(w[p], v[p].w, acc.w);
            }
        }
    }

    float ox = acc.x + __shfl(acc.x, q + 32);
    float oy = acc.y + __shfl(acc.y, q + 32);
    float oz = acc.z + __shfl(acc.z, q + 32);
    float ow = acc.w + __shfl(acc.w, q + 32);
    if (half == 0)
        ((float4*)(dst + (size_t)node * HD))[q] = make_float4(ox, oy, oz, ow);
}

// ---------------- MFMA GEMM (split-bf16, fp32-accurate) ----------------

template <bool RELU>
__global__ __launch_bounds__(256) void k_gemm_mfma(const float* __restrict__ A,
                                                   const unsigned short* __restrict__ Whi,
                                                   const unsigned short* __restrict__ Wlo,
                                                   const float* __restrict__ bias,
                                                   float* __restrict__ C, int nrows) {
    int l = threadIdx.x & 63;
    int w = threadIdx.x >> 6;
    int row0 = blockIdx.x * 64 + w * 16;
    int arow = row0 + (l & 15);
    int kj = (l >> 4) * 8;
    bool avalid = (arow < nrows);
    const float* ap = A + (size_t)(avalid ? arow : 0) * HD + kj;

    f32x4 acc[8];
#pragma unroll
    for (int nt = 0; nt < 8; ++nt) acc[nt] = (f32x4){0.f, 0.f, 0.f, 0.f};

#pragma unroll
    for (int ks = 0; ks < 4; ++ks) {
        float4 a0 = make_float4(0.f, 0.f, 0.f, 0.f), a1 = a0;
        if (avalid) {
            a0 = *(const float4*)(ap + ks * 32);
            a1 = *(const float4*)(ap + ks * 32 + 4);
        }
        float av[8] = {a0.x, a0.y, a0.z, a0.w, a1.x, a1.y, a1.z, a1.w};
        short8 ahi, alo;
#pragma unroll
        for (int j = 0; j < 8; ++j) {
            unsigned short h = rne_bf16(av[j]);
            ahi[j] = (short)h;
            alo[j] = (short)rne_bf16(av[j] - bf16_to_f32(h));
        }
#pragma unroll
        for (int nt = 0; nt < 8; ++nt) {
            size_t fo = ((size_t)(nt * 4 + ks) * 64 + l) * 8;
            short8 bhi = *(const short8*)(Whi + fo);
            short8 blo = *(const short8*)(Wlo + fo);
            acc[nt] = __builtin_amdgcn_mfma_f32_16x16x32_bf16(ahi, bhi, acc[nt], 0, 0, 0);
            acc[nt] = __builtin_amdgcn_mfma_f32_16x16x32_bf16(alo, bhi, acc[nt], 0, 0, 0);
            acc[nt] = __builtin_amdgcn_mfma_f32_16x16x32_bf16(ahi, blo, acc[nt], 0, 0, 0);
        }
    }

#pragma unroll
    for (int nt = 0; nt < 8; ++nt) {
        int col = nt * 16 + (l & 15);
        float bv = bias[col];
#pragma unroll
        for (int r = 0; r < 4; ++r) {
            int gr = row0 + (l >> 4) * 4 + r;
            if (gr >= nrows) continue;
            float v = acc[nt][r] + bv;
            if (RELU) v = fmaxf(v, 0.f);
            C[(size_t)gr * HD + col] = v;
        }
    }
}

// ---------------- launch ----------------

extern "C" void kernel_launch(void* const* d_in, const int* in_sizes, int n_in,
                              void* d_out, int out_size, void* d_ws, size_t ws_size,
                              hipStream_t stream) {
    const float* x  = (const float*)d_in[0];
    const int*   ei = (const int*)d_in[1];
    const float* W1 = (const float*)d_in[2];
    const float* b1 = (const float*)d_in[3];
    const float* W2 = (const float*)d_in[4];
    const float* b2 = (const float*)d_in[5];
    float* out = (float*)d_out;

    char* ws = (char*)d_ws;
    size_t off = 0;
    auto alloc = [&](size_t bytes) {
        void* p = ws + off;
        off = (off + bytes + 255) & ~(size_t)255;
        return p;
    };
    int*   bcur = (int*)alloc(NBK * 4);            // zeroed by memset
    int*   deg  = (int*)alloc(NN * 4);
    int*   offs = (int*)alloc(NN * 4);
    float* dinv = (float*)alloc(NN * 4);
    int*   csr  = (int*)alloc((size_t)NE * 4);
    // pairs and h overlap: pairs (12.85MB) dead before gemm1 writes h (25.6MB)
    char*  region = (char*)alloc((size_t)NN * HD * 4);
    int2*  pairs = (int2*)region;
    float* h     = (float*)region;
    float* t1   = (float*)alloc((size_t)NN * HD * 4);
    unsigned short* Whi1 = (unsigned short*)alloc(16384 * 2);
    unsigned short* Wlo1 = (unsigned short*)alloc(16384 * 2);
    unsigned short* Whi2 = (unsigned short*)alloc(16384 * 2);
    unsigned short* Wlo2 = (unsigned short*)alloc(16384 * 2);

    // CSR build: 2 dispatches + 1 tiny memset (deg computed inside fill2)
    hipMemsetAsync(bcur, 0, NBK * 4, stream);
    k_fill1<<<FB + 16, 256, 0, stream>>>(ei, bcur, pairs, W1, W2, Whi1, Wlo1, Whi2, Wlo2);
    k_fill2<<<NBK, 256, 0, stream>>>(pairs, bcur, deg, offs, dinv, csr);

    // conv1: t1 = agg(x); h = relu(t1@W1 + b1)
    k_agg_csr<<<NN / 4, 256, 0, stream>>>(x, csr, offs, deg, dinv, t1);
    k_gemm_mfma<true><<<(NN + 63) / 64, 256, 0, stream>>>(t1, Whi1, Wlo1, b1, h, NN);

    // conv2: t1 = agg(h); out = t1@W2 + b2
    k_agg_csr<<<NN / 4, 256, 0, stream>>>(h, csr, offs, deg, dinv, t1);
    k_gemm_mfma<false><<<(NN + 63) / 64, 256, 0, stream>>>(t1, Whi2, Wlo2, b2, out, NN);
}

// Round 12
// 216.762 us; speedup vs baseline: 1.5321x; 1.2890x over previous
//
#include <hip/hip_runtime.h>

#define NN 50000
#define NE 800000
#define HD 128
#define NBK 98     // ceil(NN/512) dst-buckets
#define BCAP 16384 // fixed pairs capacity per bucket
#define FB 196     // fill1 edge blocks (196*4096 >= NE)
#define CVB 200    // x->bf16 convert blocks folded into fill1

using short8 = __attribute__((ext_vector_type(8))) short;
using f32x4  = __attribute__((ext_vector_type(4))) float;

__device__ inline unsigned short rne_bf16(float v) {
    union { float f; unsigned u; } c; c.f = v;
    return (unsigned short)((c.u + 0x7fff + ((c.u >> 16) & 1)) >> 16);
}
__device__ inline float bf16_to_f32(unsigned short h) {
    union { unsigned u; float f; } c; c.u = ((unsigned)h) << 16;
    return c.f;
}

// ---------------- 1: bin edges + prepw + x->bf16 convert ----------------
// blocks [0,FB): edge binning. [FB,FB+16): weight prep. [FB+16,FB+16+CVB): x cvt.

__global__ __launch_bounds__(256) void k_fill1(const int* __restrict__ ei,
                                               int* __restrict__ bcur,
                                               int2* __restrict__ pairs,
                                               const float* __restrict__ W1,
                                               const float* __restrict__ W2,
                                               unsigned short* __restrict__ hi1,
                                               unsigned short* __restrict__ lo1,
                                               unsigned short* __restrict__ hi2,
                                               unsigned short* __restrict__ lo2,
                                               const float* __restrict__ x,
                                               unsigned short* __restrict__ xb) {
    int t = threadIdx.x, b = blockIdx.x;
    if (b >= FB + 16) {  // ---- x -> bf16 convert path ----
        int bb = b - (FB + 16);
        const int total = NN * HD / 8;  // ushort8 groups
        for (int i = bb * 256 + t; i < total; i += CVB * 256) {
            float4 a0 = ((const float4*)x)[i * 2];
            float4 a1 = ((const float4*)x)[i * 2 + 1];
            short8 r;
            r[0] = (short)rne_bf16(a0.x); r[1] = (short)rne_bf16(a0.y);
            r[2] = (short)rne_bf16(a0.z); r[3] = (short)rne_bf16(a0.w);
            r[4] = (short)rne_bf16(a1.x); r[5] = (short)rne_bf16(a1.y);
            r[6] = (short)rne_bf16(a1.z); r[7] = (short)rne_bf16(a1.w);
            *(short8*)(xb + (size_t)i * 8) = r;
        }
        return;
    }
    if (b >= FB) {  // ---- prepw path ----
        int bb = b - FB;
        const float* W = (bb < 8) ? W1 : W2;
        unsigned short* hi = (bb < 8) ? hi1 : hi2;
        unsigned short* lo = (bb < 8) ? lo1 : lo2;
        int tid = (bb & 7) * 256 + t;  // 0..2047
        int lane = tid & 63;
        int ks = (tid >> 6) & 3;
        int nt = tid >> 8;
        int n = nt * 16 + (lane & 15);
        int k0 = ks * 32 + (lane >> 4) * 8;
#pragma unroll
        for (int j = 0; j < 8; ++j) {
            float v = W[(k0 + j) * HD + n];
            unsigned short h = rne_bf16(v);
            float rem = v - bf16_to_f32(h);
            hi[(size_t)tid * 8 + j] = h;
            lo[(size_t)tid * 8 + j] = rne_bf16(rem);
        }
        return;
    }
    // ---- binning path ----
    __shared__ int dr[4096], sc[4096];
    __shared__ int hist[NBK], base[NBK];
    for (int i = t; i < NBK; i += 256) hist[i] = 0;
    __syncthreads();
    int e0 = b * 4096;
#pragma unroll
    for (int u = 0; u < 16; ++u) {
        int idx = u * 256 + t, e = e0 + idx;
        int r = -1, c = 0;
        if (e < NE) {
            r = ei[e];
            c = ei[NE + e];
            atomicAdd(&hist[r >> 9], 1);
        }
        dr[idx] = r;
        sc[idx] = c;
    }
    __syncthreads();
    for (int i = t; i < NBK; i += 256) {
        base[i] = atomicAdd(&bcur[i], hist[i]);
        hist[i] = 0;
    }
    __syncthreads();
#pragma unroll
    for (int u = 0; u < 16; ++u) {
        int idx = u * 256 + t;
        int r = dr[idx];
        if (r >= 0) {
            int bk = r >> 9;
            int pos = atomicAdd(&hist[bk], 1);
            pairs[(size_t)bk * BCAP + base[bk] + pos] = make_int2(r, sc[idx]);
        }
    }
}

// ---------------- 2: per-bucket finalize — deg + offs + dinv + csr (R11-proven) ----

__global__ __launch_bounds__(256) void k_fill2(const int2* __restrict__ pairs,
                                               const int* __restrict__ bcur,
                                               int* __restrict__ deg,
                                               int* __restrict__ offs,
                                               float* __restrict__ dinv,
                                               int* __restrict__ csr) {
    __shared__ int spart[256];
    __shared__ int cnt[512];
    __shared__ int lcur[512];
    int b = blockIdx.x, t = threadIdx.x;
    int n0 = b * 512;
    int nodes = min(512, NN - n0);

    int v = (t < NBK && t < b) ? bcur[t] : 0;
    spart[t] = v;
    __syncthreads();
#pragma unroll
    for (int o = 128; o > 0; o >>= 1) {
        if (t < o) spart[t] += spart[t + o];
        __syncthreads();
    }
    int base = spart[0];
    int tot = bcur[b];

    for (int i = t; i < 512; i += 256) cnt[i] = 0;
    __syncthreads();
    const int2* pp = pairs + (size_t)b * BCAP;
    for (int p = t; p < tot; p += 256) atomicAdd(&cnt[pp[p].x - n0], 1);
    __syncthreads();

    int d0 = (2 * t < nodes) ? cnt[2 * t] : 0;
    int d1 = (2 * t + 1 < nodes) ? cnt[2 * t + 1] : 0;
    spart[t] = d0 + d1;
    __syncthreads();
#pragma unroll
    for (int o = 1; o < 256; o <<= 1) {
        int x = (t >= o) ? spart[t - o] : 0;
        __syncthreads();
        spart[t] += x;
        __syncthreads();
    }
    int excl = spart[t] - (d0 + d1);
    int o0 = base + excl, o1 = o0 + d0;
    if (2 * t < nodes) {
        offs[n0 + 2 * t] = o0;
        lcur[2 * t] = o0;
        deg[n0 + 2 * t] = d0;
        dinv[n0 + 2 * t] = rsqrtf((float)(d0 + 1));
    }
    if (2 * t + 1 < nodes) {
        offs[n0 + 2 * t + 1] = o1;
        lcur[2 * t + 1] = o1;
        deg[n0 + 2 * t + 1] = d1;
        dinv[n0 + 2 * t + 1] = rsqrtf((float)(d1 + 1));
    }
    __syncthreads();

    for (int p = t; p < tot; p += 256) {
        int2 pr = pp[p];
        int slot = atomicAdd(&lcur[pr.x - n0], 1);
        csr[slot] = pr.y;
    }
}

// ---------------- aggregation: bf16 src/dst, quarter-wave per row, 4 edges/instr ----

__global__ __launch_bounds__(256) void k_agg_bf16(const unsigned short* __restrict__ src,
                                                  const int* __restrict__ csr,
                                                  const int* __restrict__ offs,
                                                  const int* __restrict__ deg,
                                                  const float* __restrict__ dinv,
                                                  unsigned short* __restrict__ dst) {
    int node = blockIdx.x * 4 + (threadIdx.x >> 6);
    int lane = threadIdx.x & 63;
    int q = lane >> 4;    // quarter: which edge within group of 4
    int sub = lane & 15;  // column block: cols [sub*8, sub*8+8)
    int o = offs[node];
    int dg = deg[node];
    float d = dinv[node];

    float acc[8];
    if (q == 0) {
        float s = d * d;
        short8 v = *(const short8*)(src + (size_t)node * HD + sub * 8);
#pragma unroll
        for (int i = 0; i < 8; ++i) acc[i] = s * bf16_to_f32((unsigned short)v[i]);
    } else {
#pragma unroll
        for (int i = 0; i < 8; ++i) acc[i] = 0.0f;
    }

    for (int base = 0; base < dg; base += 64) {
        int n = min(64, dg - base);
        int myc = (lane < n) ? csr[o + base + lane] : node;
        float myw = (lane < n) ? d * dinv[myc] : 0.0f;
        for (int j = 0; j * 4 < n; ++j) {
            int c = __shfl(myc, j * 4 + q);
            float w = __shfl(myw, j * 4 + q);
            short8 v = *(const short8*)(src + (size_t)c * HD + sub * 8);
#pragma unroll
            for (int i = 0; i < 8; ++i)
                acc[i] = fmaf(w, bf16_to_f32((unsigned short)v[i]), acc[i]);
        }
    }

#pragma unroll
    for (int i = 0; i < 8; ++i) {
        acc[i] += __shfl_xor(acc[i], 16);
        acc[i] += __shfl_xor(acc[i], 32);
    }
    if (q == 0) {
        short8 r;
#pragma unroll
        for (int i = 0; i < 8; ++i) r[i] = (short)rne_bf16(acc[i]);
        *(short8*)(dst + (size_t)node * HD + sub * 8) = r;
    }
}

// ---------------- MFMA GEMM: bf16 A (exact), hi/lo W, fp32 or bf16 out ----------------

template <bool RELU, bool OUTBF16>
__global__ __launch_bounds__(256) void k_gemm_mfma(const unsigned short* __restrict__ A,
                                                   const unsigned short* __restrict__ Whi,
                                                   const unsigned short* __restrict__ Wlo,
                                                   const float* __restrict__ bias,
                                                   void* __restrict__ Cout, int nrows) {
    int l = threadIdx.x & 63;
    int w = threadIdx.x >> 6;
    int row0 = blockIdx.x * 64 + w * 16;
    int arow = row0 + (l & 15);
    int kj = (l >> 4) * 8;
    bool avalid = (arow < nrows);
    const unsigned short* ap = A + (size_t)(avalid ? arow : 0) * HD + kj;

    f32x4 acc[8];
#pragma unroll
    for (int nt = 0; nt < 8; ++nt) acc[nt] = (f32x4){0.f, 0.f, 0.f, 0.f};

#pragma unroll
    for (int ks = 0; ks < 4; ++ks) {
        short8 ahi = {0, 0, 0, 0, 0, 0, 0, 0};
        if (avalid) ahi = *(const short8*)(ap + ks * 32);
#pragma unroll
        for (int nt = 0; nt < 8; ++nt) {
            size_t fo = ((size_t)(nt * 4 + ks) * 64 + l) * 8;
            short8 bhi = *(const short8*)(Whi + fo);
            short8 blo = *(const short8*)(Wlo + fo);
            acc[nt] = __builtin_amdgcn_mfma_f32_16x16x32_bf16(ahi, bhi, acc[nt], 0, 0, 0);
            acc[nt] = __builtin_amdgcn_mfma_f32_16x16x32_bf16(ahi, blo, acc[nt], 0, 0, 0);
        }
    }

#pragma unroll
    for (int nt = 0; nt < 8; ++nt) {
        int col = nt * 16 + (l & 15);
        float bv = bias[col];
#pragma unroll
        for (int r = 0; r < 4; ++r) {
            int gr = row0 + (l >> 4) * 4 + r;
            if (gr >= nrows) continue;
            float v = acc[nt][r] + bv;
            if (RELU) v = fmaxf(v, 0.f);
            if (OUTBF16)
                ((unsigned short*)Cout)[(size_t)gr * HD + col] = rne_bf16(v);
            else
                ((float*)Cout)[(size_t)gr * HD + col] = v;
        }
    }
}

// ---------------- launch ----------------

extern "C" void kernel_launch(void* const* d_in, const int* in_sizes, int n_in,
                              void* d_out, int out_size, void* d_ws, size_t ws_size,
                              hipStream_t stream) {
    const float* x  = (const float*)d_in[0];
    const int*   ei = (const int*)d_in[1];
    const float* W1 = (const float*)d_in[2];
    const float* b1 = (const float*)d_in[3];
    const float* W2 = (const float*)d_in[4];
    const float* b2 = (const float*)d_in[5];
    float* out = (float*)d_out;

    char* ws = (char*)d_ws;
    size_t off = 0;
    auto alloc = [&](size_t bytes) {
        void* p = ws + off;
        off = (off + bytes + 255) & ~(size_t)255;
        return p;
    };
    int*   bcur = (int*)alloc(NBK * 4);  // zeroed by memset
    int*   deg  = (int*)alloc(NN * 4);
    int*   offs = (int*)alloc(NN * 4);
    float* dinv = (float*)alloc(NN * 4);
    int*   csr  = (int*)alloc((size_t)NE * 4);
    unsigned short* xb  = (unsigned short*)alloc((size_t)NN * HD * 2);
    unsigned short* t1b = (unsigned short*)alloc((size_t)NN * HD * 2);
    // pairs and hb overlap: pairs (12.85MB) dead before gemm1 writes hb (12.8MB)
    char* region = (char*)alloc((size_t)NBK * BCAP * 8);
    int2* pairs = (int2*)region;
    unsigned short* hb = (unsigned short*)region;
    unsigned short* Whi1 = (unsigned short*)alloc(16384 * 2);
    unsigned short* Wlo1 = (unsigned short*)alloc(16384 * 2);
    unsigned short* Whi2 = (unsigned short*)alloc(16384 * 2);
    unsigned short* Wlo2 = (unsigned short*)alloc(16384 * 2);

    // CSR build + weight prep + x convert: 2 dispatches + 1 tiny memset
    hipMemsetAsync(bcur, 0, NBK * 4, stream);
    k_fill1<<<FB + 16 + CVB, 256, 0, stream>>>(ei, bcur, pairs, W1, W2,
                                               Whi1, Wlo1, Whi2, Wlo2, x, xb);
    k_fill2<<<NBK, 256, 0, stream>>>(pairs, bcur, deg, offs, dinv, csr);

    // conv1: t1b = agg(xb); hb = relu(t1b@W1 + b1) [bf16]
    k_agg_bf16<<<NN / 4, 256, 0, stream>>>(xb, csr, offs, deg, dinv, t1b);
    k_gemm_mfma<true, true><<<(NN + 63) / 64, 256, 0, stream>>>(t1b, Whi1, Wlo1, b1, hb, NN);

    // conv2: t1b = agg(hb); out = t1b@W2 + b2 [fp32 out]
    k_agg_bf16<<<NN / 4, 256, 0, stream>>>(hb, csr, offs, deg, dinv, t1b);
    k_gemm_mfma<false, false><<<(NN + 63) / 64, 256, 0, stream>>>(t1b, Whi2, Wlo2, b2, out, NN);
}

// Round 13
// 201.024 us; speedup vs baseline: 1.6521x; 1.0783x over previous
//
#include <hip/hip_runtime.h>

#define NN 50000
#define NE 800000
#define HD 128
#define NBK 98     // ceil(NN/512) dst-buckets
#define BCAP 16384 // fixed pairs capacity per bucket
#define FB 196     // fill1 edge blocks (196*4096 >= NE)
#define CVB 200    // x->bf16 convert blocks folded into fill1

using short8 = __attribute__((ext_vector_type(8))) short;
using f32x4  = __attribute__((ext_vector_type(4))) float;

__device__ inline unsigned short rne_bf16(float v) {
    union { float f; unsigned u; } c; c.f = v;
    return (unsigned short)((c.u + 0x7fff + ((c.u >> 16) & 1)) >> 16);
}
__device__ inline float bf16_to_f32(unsigned short h) {
    union { unsigned u; float f; } c; c.u = ((unsigned)h) << 16;
    return c.f;
}

// ---------------- 1: bin edges + prepw + x->bf16 convert (R12-proven) ----------------

__global__ __launch_bounds__(256) void k_fill1(const int* __restrict__ ei,
                                               int* __restrict__ bcur,
                                               int2* __restrict__ pairs,
                                               const float* __restrict__ W1,
                                               const float* __restrict__ W2,
                                               unsigned short* __restrict__ hi1,
                                               unsigned short* __restrict__ lo1,
                                               unsigned short* __restrict__ hi2,
                                               unsigned short* __restrict__ lo2,
                                               const float* __restrict__ x,
                                               unsigned short* __restrict__ xb) {
    int t = threadIdx.x, b = blockIdx.x;
    if (b >= FB + 16) {  // ---- x -> bf16 convert path ----
        int bb = b - (FB + 16);
        const int total = NN * HD / 8;
        for (int i = bb * 256 + t; i < total; i += CVB * 256) {
            float4 a0 = ((const float4*)x)[i * 2];
            float4 a1 = ((const float4*)x)[i * 2 + 1];
            short8 r;
            r[0] = (short)rne_bf16(a0.x); r[1] = (short)rne_bf16(a0.y);
            r[2] = (short)rne_bf16(a0.z); r[3] = (short)rne_bf16(a0.w);
            r[4] = (short)rne_bf16(a1.x); r[5] = (short)rne_bf16(a1.y);
            r[6] = (short)rne_bf16(a1.z); r[7] = (short)rne_bf16(a1.w);
            *(short8*)(xb + (size_t)i * 8) = r;
        }
        return;
    }
    if (b >= FB) {  // ---- prepw path ----
        int bb = b - FB;
        const float* W = (bb < 8) ? W1 : W2;
        unsigned short* hi = (bb < 8) ? hi1 : hi2;
        unsigned short* lo = (bb < 8) ? lo1 : lo2;
        int tid = (bb & 7) * 256 + t;
        int lane = tid & 63;
        int ks = (tid >> 6) & 3;
        int nt = tid >> 8;
        int n = nt * 16 + (lane & 15);
        int k0 = ks * 32 + (lane >> 4) * 8;
#pragma unroll
        for (int j = 0; j < 8; ++j) {
            float v = W[(k0 + j) * HD + n];
            unsigned short h = rne_bf16(v);
            float rem = v - bf16_to_f32(h);
            hi[(size_t)tid * 8 + j] = h;
            lo[(size_t)tid * 8 + j] = rne_bf16(rem);
        }
        return;
    }
    // ---- binning path ----
    __shared__ int dr[4096], sc[4096];
    __shared__ int hist[NBK], base[NBK];
    for (int i = t; i < NBK; i += 256) hist[i] = 0;
    __syncthreads();
    int e0 = b * 4096;
#pragma unroll
    for (int u = 0; u < 16; ++u) {
        int idx = u * 256 + t, e = e0 + idx;
        int r = -1, c = 0;
        if (e < NE) {
            r = ei[e];
            c = ei[NE + e];
            atomicAdd(&hist[r >> 9], 1);
        }
        dr[idx] = r;
        sc[idx] = c;
    }
    __syncthreads();
    for (int i = t; i < NBK; i += 256) {
        base[i] = atomicAdd(&bcur[i], hist[i]);
        hist[i] = 0;
    }
    __syncthreads();
#pragma unroll
    for (int u = 0; u < 16; ++u) {
        int idx = u * 256 + t;
        int r = dr[idx];
        if (r >= 0) {
            int bk = r >> 9;
            int pos = atomicAdd(&hist[bk], 1);
            pairs[(size_t)bk * BCAP + base[bk] + pos] = make_int2(r, sc[idx]);
        }
    }
}

// ---------------- 2: per-bucket finalize (R11-proven) ----------------

__global__ __launch_bounds__(256) void k_fill2(const int2* __restrict__ pairs,
                                               const int* __restrict__ bcur,
                                               int* __restrict__ deg,
                                               int* __restrict__ offs,
                                               float* __restrict__ dinv,
                                               int* __restrict__ csr) {
    __shared__ int spart[256];
    __shared__ int cnt[512];
    __shared__ int lcur[512];
    int b = blockIdx.x, t = threadIdx.x;
    int n0 = b * 512;
    int nodes = min(512, NN - n0);

    int v = (t < NBK && t < b) ? bcur[t] : 0;
    spart[t] = v;
    __syncthreads();
#pragma unroll
    for (int o = 128; o > 0; o >>= 1) {
        if (t < o) spart[t] += spart[t + o];
        __syncthreads();
    }
    int base = spart[0];
    int tot = bcur[b];

    for (int i = t; i < 512; i += 256) cnt[i] = 0;
    __syncthreads();
    const int2* pp = pairs + (size_t)b * BCAP;
    for (int p = t; p < tot; p += 256) atomicAdd(&cnt[pp[p].x - n0], 1);
    __syncthreads();

    int d0 = (2 * t < nodes) ? cnt[2 * t] : 0;
    int d1 = (2 * t + 1 < nodes) ? cnt[2 * t + 1] : 0;
    spart[t] = d0 + d1;
    __syncthreads();
#pragma unroll
    for (int o = 1; o < 256; o <<= 1) {
        int x = (t >= o) ? spart[t - o] : 0;
        __syncthreads();
        spart[t] += x;
        __syncthreads();
    }
    int excl = spart[t] - (d0 + d1);
    int o0 = base + excl, o1 = o0 + d0;
    if (2 * t < nodes) {
        offs[n0 + 2 * t] = o0;
        lcur[2 * t] = o0;
        deg[n0 + 2 * t] = d0;
        dinv[n0 + 2 * t] = rsqrtf((float)(d0 + 1));
    }
    if (2 * t + 1 < nodes) {
        offs[n0 + 2 * t + 1] = o1;
        lcur[2 * t + 1] = o1;
        deg[n0 + 2 * t + 1] = d1;
        dinv[n0 + 2 * t + 1] = rsqrtf((float)(d1 + 1));
    }
    __syncthreads();

    for (int p = t; p < tot; p += 256) {
        int2 pr = pp[p];
        int slot = atomicAdd(&lcur[pr.x - n0], 1);
        csr[slot] = pr.y;
    }
}

// ---------------- fused agg + MFMA GEMM ----------------
// block = 16 nodes; phase A: 4 waves x 4 nodes gather (R12 structure) -> LDS
// (bf16, XOR-swizzled rows); phase B: 16x128 GEMM, A from LDS, exact-bf16 A
// with hi/lo W (2 MFMAs per tile). Wave w covers col-tiles nt=2w,2w+1.

template <bool RELU, bool OUTBF16>
__global__ __launch_bounds__(256) void k_agg_gemm(const unsigned short* __restrict__ src,
                                                  const int* __restrict__ csr,
                                                  const int* __restrict__ offs,
                                                  const int* __restrict__ deg,
                                                  const float* __restrict__ dinv,
                                                  const unsigned short* __restrict__ Whi,
                                                  const unsigned short* __restrict__ Wlo,
                                                  const float* __restrict__ bias,
                                                  void* __restrict__ Cout) {
    __shared__ unsigned short As[16 * 128];  // 4KB, rows 256B, XOR-swizzled slots
    int t = threadIdx.x;
    int w = t >> 6, l = t & 63;
    int q = l >> 4, sub = l & 15;
    int n0 = blockIdx.x * 16;

    // ---- phase A: aggregate 4 nodes per wave ----
#pragma unroll
    for (int i = 0; i < 4; ++i) {
        int row = w * 4 + i;
        int node = n0 + row;
        int o = offs[node];
        int dg = deg[node];
        float d = dinv[node];

        float acc[8];
        if (q == 0) {
            float s = d * d;
            short8 v = *(const short8*)(src + (size_t)node * HD + sub * 8);
#pragma unroll
            for (int k = 0; k < 8; ++k) acc[k] = s * bf16_to_f32((unsigned short)v[k]);
        } else {
#pragma unroll
            for (int k = 0; k < 8; ++k) acc[k] = 0.0f;
        }

        for (int base = 0; base < dg; base += 64) {
            int n = min(64, dg - base);
            int myc = (l < n) ? csr[o + base + l] : node;
            float myw = (l < n) ? d * dinv[myc] : 0.0f;
            for (int j = 0; j * 4 < n; ++j) {
                int c = __shfl(myc, j * 4 + q);
                float wg = __shfl(myw, j * 4 + q);
                short8 v = *(const short8*)(src + (size_t)c * HD + sub * 8);
#pragma unroll
                for (int k = 0; k < 8; ++k)
                    acc[k] = fmaf(wg, bf16_to_f32((unsigned short)v[k]), acc[k]);
            }
        }
#pragma unroll
        for (int k = 0; k < 8; ++k) {
            acc[k] += __shfl_xor(acc[k], 16);
            acc[k] += __shfl_xor(acc[k], 32);
        }
        if (q == 0) {
            short8 r;
#pragma unroll
            for (int k = 0; k < 8; ++k) r[k] = (short)rne_bf16(acc[k]);
            int byte = (sub * 16) ^ ((row & 7) << 4);
            *(short8*)((char*)As + row * 256 + byte) = r;
        }
    }
    __syncthreads();

    // ---- phase B: GEMM 16x128, A from LDS ----
    f32x4 cacc[2];
    cacc[0] = (f32x4){0.f, 0.f, 0.f, 0.f};
    cacc[1] = (f32x4){0.f, 0.f, 0.f, 0.f};
    int arow = l & 15;
#pragma unroll
    for (int ks = 0; ks < 4; ++ks) {
        int byte = (ks * 64 + (l >> 4) * 16) ^ ((arow & 7) << 4);
        short8 ahi = *(const short8*)((char*)As + arow * 256 + byte);
#pragma unroll
        for (int i = 0; i < 2; ++i) {
            int nt = w * 2 + i;
            size_t fo = ((size_t)(nt * 4 + ks) * 64 + l) * 8;
            short8 bhi = *(const short8*)(Whi + fo);
            short8 blo = *(const short8*)(Wlo + fo);
            cacc[i] = __builtin_amdgcn_mfma_f32_16x16x32_bf16(ahi, bhi, cacc[i], 0, 0, 0);
            cacc[i] = __builtin_amdgcn_mfma_f32_16x16x32_bf16(ahi, blo, cacc[i], 0, 0, 0);
        }
    }

#pragma unroll
    for (int i = 0; i < 2; ++i) {
        int nt = w * 2 + i;
        int col = nt * 16 + (l & 15);
        float bv = bias[col];
#pragma unroll
        for (int r = 0; r < 4; ++r) {
            int gr = n0 + (l >> 4) * 4 + r;
            float v = cacc[i][r] + bv;
            if (RELU) v = fmaxf(v, 0.f);
            if (OUTBF16)
                ((unsigned short*)Cout)[(size_t)gr * HD + col] = rne_bf16(v);
            else
                ((float*)Cout)[(size_t)gr * HD + col] = v;
        }
    }
}

// ---------------- launch ----------------

extern "C" void kernel_launch(void* const* d_in, const int* in_sizes, int n_in,
                              void* d_out, int out_size, void* d_ws, size_t ws_size,
                              hipStream_t stream) {
    const float* x  = (const float*)d_in[0];
    const int*   ei = (const int*)d_in[1];
    const float* W1 = (const float*)d_in[2];
    const float* b1 = (const float*)d_in[3];
    const float* W2 = (const float*)d_in[4];
    const float* b2 = (const float*)d_in[5];
    float* out = (float*)d_out;

    char* ws = (char*)d_ws;
    size_t off = 0;
    auto alloc = [&](size_t bytes) {
        void* p = ws + off;
        off = (off + bytes + 255) & ~(size_t)255;
        return p;
    };
    int*   bcur = (int*)alloc(NBK * 4);  // zeroed by memset
    int*   deg  = (int*)alloc(NN * 4);
    int*   offs = (int*)alloc(NN * 4);
    float* dinv = (float*)alloc(NN * 4);
    int*   csr  = (int*)alloc((size_t)NE * 4);
    unsigned short* xb = (unsigned short*)alloc((size_t)NN * HD * 2);
    // pairs and hb overlap: pairs dead after fill2; fused1 then writes hb here
    char* region = (char*)alloc((size_t)NBK * BCAP * 8);
    int2* pairs = (int2*)region;
    unsigned short* hb = (unsigned short*)region;
    unsigned short* Whi1 = (unsigned short*)alloc(16384 * 2);
    unsigned short* Wlo1 = (unsigned short*)alloc(16384 * 2);
    unsigned short* Whi2 = (unsigned short*)alloc(16384 * 2);
    unsigned short* Wlo2 = (unsigned short*)alloc(16384 * 2);

    // CSR build + weight prep + x convert
    hipMemsetAsync(bcur, 0, NBK * 4, stream);
    k_fill1<<<FB + 16 + CVB, 256, 0, stream>>>(ei, bcur, pairs, W1, W2,
                                               Whi1, Wlo1, Whi2, Wlo2, x, xb);
    k_fill2<<<NBK, 256, 0, stream>>>(pairs, bcur, deg, offs, dinv, csr);

    // conv1 fused: hb = relu(agg(xb)@W1 + b1) [bf16 out]
    k_agg_gemm<true, true><<<NN / 16, 256, 0, stream>>>(xb, csr, offs, deg, dinv,
                                                        Whi1, Wlo1, b1, hb);
    // conv2 fused: out = agg(hb)@W2 + b2 [fp32 out]
    k_agg_gemm<false, false><<<NN / 16, 256, 0, stream>>>(hb, csr, offs, deg, dinv,
                                                          Whi2, Wlo2, b2, out);
}

// Round 14
// 199.183 us; speedup vs baseline: 1.6674x; 1.0092x over previous
//
#include <hip/hip_runtime.h>

#define NN 50000
#define NE 800000
#define HD 128
#define NBK 98     // ceil(NN/512) dst-buckets
#define BCAP 16384 // fixed pairs capacity per bucket
#define FB 196     // fill1 edge blocks (196*4096 >= NE)
#define CVB 200    // x->bf16 convert blocks folded into fill1

using short8 = __attribute__((ext_vector_type(8))) short;
using f32x4  = __attribute__((ext_vector_type(4))) float;

__device__ inline unsigned short rne_bf16(float v) {
    union { float f; unsigned u; } c; c.f = v;
    return (unsigned short)((c.u + 0x7fff + ((c.u >> 16) & 1)) >> 16);
}
__device__ inline float bf16_to_f32(unsigned short h) {
    union { unsigned u; float f; } c; c.u = ((unsigned)h) << 16;
    return c.f;
}

// ---------------- 1: bin edges + prepw + x->bf16 convert ----------------
// pairs packed: (dst_local<<16) | src  (src < 50000 < 2^16, dst_local < 512)

__global__ __launch_bounds__(256) void k_fill1(const int* __restrict__ ei,
                                               int* __restrict__ bcur,
                                               int* __restrict__ pairs,
                                               const float* __restrict__ W1,
                                               const float* __restrict__ W2,
                                               unsigned short* __restrict__ hi1,
                                               unsigned short* __restrict__ lo1,
                                               unsigned short* __restrict__ hi2,
                                               unsigned short* __restrict__ lo2,
                                               const float* __restrict__ x,
                                               unsigned short* __restrict__ xb) {
    int t = threadIdx.x, b = blockIdx.x;
    if (b >= FB + 16) {  // ---- x -> bf16 convert path ----
        int bb = b - (FB + 16);
        const int total = NN * HD / 8;
        for (int i = bb * 256 + t; i < total; i += CVB * 256) {
            float4 a0 = ((const float4*)x)[i * 2];
            float4 a1 = ((const float4*)x)[i * 2 + 1];
            short8 r;
            r[0] = (short)rne_bf16(a0.x); r[1] = (short)rne_bf16(a0.y);
            r[2] = (short)rne_bf16(a0.z); r[3] = (short)rne_bf16(a0.w);
            r[4] = (short)rne_bf16(a1.x); r[5] = (short)rne_bf16(a1.y);
            r[6] = (short)rne_bf16(a1.z); r[7] = (short)rne_bf16(a1.w);
            *(short8*)(xb + (size_t)i * 8) = r;
        }
        return;
    }
    if (b >= FB) {  // ---- prepw path ----
        int bb = b - FB;
        const float* W = (bb < 8) ? W1 : W2;
        unsigned short* hi = (bb < 8) ? hi1 : hi2;
        unsigned short* lo = (bb < 8) ? lo1 : lo2;
        int tid = (bb & 7) * 256 + t;
        int lane = tid & 63;
        int ks = (tid >> 6) & 3;
        int nt = tid >> 8;
        int n = nt * 16 + (lane & 15);
        int k0 = ks * 32 + (lane >> 4) * 8;
#pragma unroll
        for (int j = 0; j < 8; ++j) {
            float v = W[(k0 + j) * HD + n];
            unsigned short h = rne_bf16(v);
            float rem = v - bf16_to_f32(h);
            hi[(size_t)tid * 8 + j] = h;
            lo[(size_t)tid * 8 + j] = rne_bf16(rem);
        }
        return;
    }
    // ---- binning path ----
    __shared__ int dr[4096], sc[4096];
    __shared__ int hist[NBK], base[NBK];
    for (int i = t; i < NBK; i += 256) hist[i] = 0;
    __syncthreads();
    int e0 = b * 4096;
#pragma unroll
    for (int u = 0; u < 16; ++u) {
        int idx = u * 256 + t, e = e0 + idx;
        int r = -1, c = 0;
        if (e < NE) {
            r = ei[e];
            c = ei[NE + e];
            atomicAdd(&hist[r >> 9], 1);
        }
        dr[idx] = r;
        sc[idx] = c;
    }
    __syncthreads();
    for (int i = t; i < NBK; i += 256) {
        base[i] = atomicAdd(&bcur[i], hist[i]);
        hist[i] = 0;
    }
    __syncthreads();
#pragma unroll
    for (int u = 0; u < 16; ++u) {
        int idx = u * 256 + t;
        int r = dr[idx];
        if (r >= 0) {
            int bk = r >> 9;
            int pos = atomicAdd(&hist[bk], 1);
            pairs[(size_t)bk * BCAP + base[bk] + pos] = ((r & 511) << 16) | sc[idx];
        }
    }
}

// ---------------- 2: per-bucket finalize — deg + offs + dinv + csr ----------------

__global__ __launch_bounds__(256) void k_fill2(const int* __restrict__ pairs,
                                               const int* __restrict__ bcur,
                                               int* __restrict__ deg,
                                               int* __restrict__ offs,
                                               float* __restrict__ dinv,
                                               int* __restrict__ csr) {
    __shared__ int spart[256];
    __shared__ int cnt[512];
    __shared__ int lcur[512];
    int b = blockIdx.x, t = threadIdx.x;
    int n0 = b * 512;
    int nodes = min(512, NN - n0);

    int v = (t < NBK && t < b) ? bcur[t] : 0;
    spart[t] = v;
    __syncthreads();
#pragma unroll
    for (int o = 128; o > 0; o >>= 1) {
        if (t < o) spart[t] += spart[t + o];
        __syncthreads();
    }
    int base = spart[0];
    int tot = bcur[b];

    for (int i = t; i < 512; i += 256) cnt[i] = 0;
    __syncthreads();
    const int* pp = pairs + (size_t)b * BCAP;
    for (int p = t; p < tot; p += 256) atomicAdd(&cnt[pp[p] >> 16], 1);
    __syncthreads();

    int d0 = (2 * t < nodes) ? cnt[2 * t] : 0;
    int d1 = (2 * t + 1 < nodes) ? cnt[2 * t + 1] : 0;
    spart[t] = d0 + d1;
    __syncthreads();
#pragma unroll
    for (int o = 1; o < 256; o <<= 1) {
        int x = (t >= o) ? spart[t - o] : 0;
        __syncthreads();
        spart[t] += x;
        __syncthreads();
    }
    int excl = spart[t] - (d0 + d1);
    int o0 = base + excl, o1 = o0 + d0;
    if (2 * t < nodes) {
        offs[n0 + 2 * t] = o0;
        lcur[2 * t] = o0;
        deg[n0 + 2 * t] = d0;
        dinv[n0 + 2 * t] = rsqrtf((float)(d0 + 1));
    }
    if (2 * t + 1 < nodes) {
        offs[n0 + 2 * t + 1] = o1;
        lcur[2 * t + 1] = o1;
        deg[n0 + 2 * t + 1] = d1;
        dinv[n0 + 2 * t + 1] = rsqrtf((float)(d1 + 1));
    }
    __syncthreads();

    for (int p = t; p < tot; p += 256) {
        int pr = pp[p];
        int slot = atomicAdd(&lcur[pr >> 16], 1);
        csr[slot] = pr & 0xFFFF;
    }
}

// ---------------- fused agg + MFMA GEMM, 4-deep gather batching ----------------
// phase A: 4 waves x 4 nodes; quarter q handles edges {16j+q,16j+4+q,16j+8+q,16j+12+q}
// -> 4 independent short8 gathers in flight. phase B: 16x128 MFMA GEMM from LDS.

template <bool RELU, bool OUTBF16>
__global__ __launch_bounds__(256) void k_agg_gemm(const unsigned short* __restrict__ src,
                                                  const int* __restrict__ csr,
                                                  const int* __restrict__ offs,
                                                  const int* __restrict__ deg,
                                                  const float* __restrict__ dinv,
                                                  const unsigned short* __restrict__ Whi,
                                                  const unsigned short* __restrict__ Wlo,
                                                  const float* __restrict__ bias,
                                                  void* __restrict__ Cout) {
    __shared__ unsigned short As[16 * 128];  // 4KB, rows 256B, XOR-swizzled slots
    int t = threadIdx.x;
    int w = t >> 6, l = t & 63;
    int q = l >> 4, sub = l & 15;
    int n0 = blockIdx.x * 16;

    // ---- phase A ----
#pragma unroll
    for (int i = 0; i < 4; ++i) {
        int row = w * 4 + i;
        int node = n0 + row;
        int o = offs[node];
        int dg = deg[node];
        float d = dinv[node];

        float acc[8];
        if (q == 0) {
            float s = d * d;
            short8 v = *(const short8*)(src + (size_t)node * HD + sub * 8);
#pragma unroll
            for (int k = 0; k < 8; ++k) acc[k] = s * bf16_to_f32((unsigned short)v[k]);
        } else {
#pragma unroll
            for (int k = 0; k < 8; ++k) acc[k] = 0.0f;
        }

        for (int base = 0; base < dg; base += 64) {
            int n = min(64, dg - base);
            int myc = (l < n) ? csr[o + base + l] : node;
            float myw = (l < n) ? d * dinv[myc] : 0.0f;
            int jmax = (n + 15) >> 4;
            for (int j = 0; j < jmax; ++j) {
                int e = j * 16 + q;
                int c0 = __shfl(myc, e);
                int c1 = __shfl(myc, e + 4);
                int c2 = __shfl(myc, e + 8);
                int c3 = __shfl(myc, e + 12);
                float w0 = __shfl(myw, e);
                float w1 = __shfl(myw, e + 4);
                float w2 = __shfl(myw, e + 8);
                float w3 = __shfl(myw, e + 12);
                short8 v0 = *(const short8*)(src + (size_t)c0 * HD + sub * 8);
                short8 v1 = *(const short8*)(src + (size_t)c1 * HD + sub * 8);
                short8 v2 = *(const short8*)(src + (size_t)c2 * HD + sub * 8);
                short8 v3 = *(const short8*)(src + (size_t)c3 * HD + sub * 8);
#pragma unroll
                for (int k = 0; k < 8; ++k) {
                    acc[k] = fmaf(w0, bf16_to_f32((unsigned short)v0[k]), acc[k]);
                    acc[k] = fmaf(w1, bf16_to_f32((unsigned short)v1[k]), acc[k]);
                    acc[k] = fmaf(w2, bf16_to_f32((unsigned short)v2[k]), acc[k]);
                    acc[k] = fmaf(w3, bf16_to_f32((unsigned short)v3[k]), acc[k]);
                }
            }
        }
#pragma unroll
        for (int k = 0; k < 8; ++k) {
            acc[k] += __shfl_xor(acc[k], 16);
            acc[k] += __shfl_xor(acc[k], 32);
        }
        if (q == 0) {
            short8 r;
#pragma unroll
            for (int k = 0; k < 8; ++k) r[k] = (short)rne_bf16(acc[k]);
            int byte = (sub * 16) ^ ((row & 7) << 4);
            *(short8*)((char*)As + row * 256 + byte) = r;
        }
    }
    __syncthreads();

    // ---- phase B: GEMM 16x128, A from LDS ----
    f32x4 cacc[2];
    cacc[0] = (f32x4){0.f, 0.f, 0.f, 0.f};
    cacc[1] = (f32x4){0.f, 0.f, 0.f, 0.f};
    int arow = l & 15;
#pragma unroll
    for (int ks = 0; ks < 4; ++ks) {
        int byte = (ks * 64 + (l >> 4) * 16) ^ ((arow & 7) << 4);
        short8 ahi = *(const short8*)((char*)As + arow * 256 + byte);
#pragma unroll
        for (int i = 0; i < 2; ++i) {
            int nt = w * 2 + i;
            size_t fo = ((size_t)(nt * 4 + ks) * 64 + l) * 8;
            short8 bhi = *(const short8*)(Whi + fo);
            short8 blo = *(const short8*)(Wlo + fo);
            cacc[i] = __builtin_amdgcn_mfma_f32_16x16x32_bf16(ahi, bhi, cacc[i], 0, 0, 0);
            cacc[i] = __builtin_amdgcn_mfma_f32_16x16x32_bf16(ahi, blo, cacc[i], 0, 0, 0);
        }
    }

#pragma unroll
    for (int i = 0; i < 2; ++i) {
        int nt = w * 2 + i;
        int col = nt * 16 + (l & 15);
        float bv = bias[col];
#pragma unroll
        for (int r = 0; r < 4; ++r) {
            int gr = n0 + (l >> 4) * 4 + r;
            float v = cacc[i][r] + bv;
            if (RELU) v = fmaxf(v, 0.f);
            if (OUTBF16)
                ((unsigned short*)Cout)[(size_t)gr * HD + col] = rne_bf16(v);
            else
                ((float*)Cout)[(size_t)gr * HD + col] = v;
        }
    }
}

// ---------------- launch ----------------

extern "C" void kernel_launch(void* const* d_in, const int* in_sizes, int n_in,
                              void* d_out, int out_size, void* d_ws, size_t ws_size,
                              hipStream_t stream) {
    const float* x  = (const float*)d_in[0];
    const int*   ei = (const int*)d_in[1];
    const float* W1 = (const float*)d_in[2];
    const float* b1 = (const float*)d_in[3];
    const float* W2 = (const float*)d_in[4];
    const float* b2 = (const float*)d_in[5];
    float* out = (float*)d_out;

    char* ws = (char*)d_ws;
    size_t off = 0;
    auto alloc = [&](size_t bytes) {
        void* p = ws + off;
        off = (off + bytes + 255) & ~(size_t)255;
        return p;
    };
    int*   bcur = (int*)alloc(NBK * 4);  // zeroed by memset
    int*   deg  = (int*)alloc(NN * 4);
    int*   offs = (int*)alloc(NN * 4);
    float* dinv = (float*)alloc(NN * 4);
    int*   csr  = (int*)alloc((size_t)NE * 4);
    unsigned short* xb = (unsigned short*)alloc((size_t)NN * HD * 2);
    // pairs (6.4MB packed) and hb (12.8MB) overlap: pairs dead after fill2
    char* region = (char*)alloc((size_t)NN * HD * 2);
    int*  pairs = (int*)region;
    unsigned short* hb = (unsigned short*)region;
    unsigned short* Whi1 = (unsigned short*)alloc(16384 * 2);
    unsigned short* Wlo1 = (unsigned short*)alloc(16384 * 2);
    unsigned short* Whi2 = (unsigned short*)alloc(16384 * 2);
    unsigned short* Wlo2 = (unsigned short*)alloc(16384 * 2);

    // CSR build + weight prep + x convert
    hipMemsetAsync(bcur, 0, NBK * 4, stream);
    k_fill1<<<FB + 16 + CVB, 256, 0, stream>>>(ei, bcur, pairs, W1, W2,
                                               Whi1, Wlo1, Whi2, Wlo2, x, xb);
    k_fill2<<<NBK, 256, 0, stream>>>(pairs, bcur, deg, offs, dinv, csr);

    // conv1 fused: hb = relu(agg(xb)@W1 + b1) [bf16 out]
    k_agg_gemm<true, true><<<NN / 16, 256, 0, stream>>>(xb, csr, offs, deg, dinv,
                                                        Whi1, Wlo1, b1, hb);
    // conv2 fused: out = agg(hb)@W2 + b2 [fp32 out]
    k_agg_gemm<false, false><<<NN / 16, 256, 0, stream>>>(hb, csr, offs, deg, dinv,
                                                          Whi2, Wlo2, b2, out);
}